// Round 2
// baseline (642.423 us; speedup 1.0000x reference)
//
#include <hip/hip_runtime.h>

// SSIM loss, fused. R7: wave-autonomous, ZERO barriers in the main loop.
// R6 post-mortem: __syncthreads() compiles to s_waitcnt vmcnt(0) lgkmcnt(0)
// + s_barrier, so the prefetched global loads were force-drained at every
// barrier -> pipeline bought nothing (104us/dispatch, all pipes <30%).
// Fix: one 64-lane wave owns an entire 8-row x 512-col strip (8 cols/lane),
// with WAVE-PRIVATE LDS for the S (column-sum) / Q (aligned quad-sum)
// buffers. Same-wave DS ops execute in order -> no barrier needed between
// writeSQ (row r+1) and hphase reads (row r); only compiler-inserted lgkmcnt
// waits remain. Prefetched global loads are consumed one full row later and
// are never drained by a barrier.
//  - Same algebra as R5/R6: u=x+y, v=x-y -> Su,Sv,Suu,Svv (4 channels).
//  - Same two-level horizontal sums: any 11-tap window = 3 S + 2 Q reads,
//    lane-stride-1 / broadcast (R2-proven 0 LDS bank conflicts; per-wave
//    lane pattern identical to R5).
//  - STRIP=8 -> 4096 independent waves = 16/CU (LDS 10.56KB/wave caps 15).
// Per-pixel arithmetic order identical to R5/R6.

#define IMG_H 512
#define IMG_W 512
#define N_IMG 64
#define STRIP 8            // output rows per wave -> grid (64,64)=4096 blocks
#define NTHREADS 64        // one wave per block
#define SSZ 528            // S: idx = col + 8, cols -8..519 (pads zero)
#define QSZ 132            // Q: idx = m + 2,  m = -2..129  (pads zero)
#define ROWSZ (SSZ + QSZ)  // 660 floats per ch (mult of 4 -> 16B align)

__global__ __launch_bounds__(NTHREADS, 4) void ssim_kernel(const float* __restrict__ img1,
                                                           const float* __restrict__ img2,
                                                           float* __restrict__ ws) {
    __shared__ __align__(16) float V[4][ROWSZ];  // wave-private; ch: u,v,uu,vv
    const int t = threadIdx.x;                   // lane 0..63
    const int b = blockIdx.y;
    const int r0 = blockIdx.x * STRIP;
    const float* __restrict__ p1 = img1 + (size_t)b * (IMG_H * IMG_W);
    const float* __restrict__ p2 = img2 + (size_t)b * (IMG_H * IMG_W);

    // Zero all of V once (pads never written again). Same wave -> in-order
    // LDS pipe, no barrier needed.
    for (int i = t; i < 4 * ROWSZ; i += NTHREADS) (&V[0][0])[i] = 0.0f;

    // Lane owns cols c4a..c4a+3 and c4b..c4b+3 (two float4 quads).
    const int c4a = 4 * t;
    const int c4b = 4 * t + 256;
    float csA[4][4], csB[4][4];
#pragma unroll
    for (int ch = 0; ch < 4; ++ch)
#pragma unroll
        for (int j = 0; j < 4; ++j) { csA[ch][j] = 0.0f; csB[ch][j] = 0.0f; }

    auto addQ = [&](float (&cs)[4][4], float4 x, float4 y) {
        float xs[4] = {x.x, x.y, x.z, x.w}, ys[4] = {y.x, y.y, y.z, y.w};
#pragma unroll
        for (int j = 0; j < 4; ++j) {
            float u = xs[j] + ys[j], v = xs[j] - ys[j];
            cs[0][j] += u;                  cs[1][j] += v;
            cs[2][j] = fmaf(u, u, cs[2][j]); cs[3][j] = fmaf(v, v, cs[3][j]);
        }
    };
    auto subQ = [&](float (&cs)[4][4], float4 x, float4 y) {
        float xs[4] = {x.x, x.y, x.z, x.w}, ys[4] = {y.x, y.y, y.z, y.w};
#pragma unroll
        for (int j = 0; j < 4; ++j) {
            float u = xs[j] + ys[j], v = xs[j] - ys[j];
            cs[0][j] -= u;                  cs[1][j] -= v;
            cs[2][j] = fmaf(-u, u, cs[2][j]); cs[3][j] = fmaf(-v, v, cs[3][j]);
        }
    };

    // Warm vertical window for output row r0. Static 11-iter unrolled loop
    // (predicated top edge) so the compiler can issue loads ahead.
#pragma unroll
    for (int dr = -5; dr <= 5; ++dr) {
        const int r = r0 + dr;                 // r0+5 <= 509 < IMG_H always
        if (r >= 0) {
            float4 xa = *(const float4*)(p1 + (size_t)r * IMG_W + c4a);
            float4 ya = *(const float4*)(p2 + (size_t)r * IMG_W + c4a);
            float4 xb = *(const float4*)(p1 + (size_t)r * IMG_W + c4b);
            float4 yb = *(const float4*)(p2 + (size_t)r * IMG_W + c4b);
            addQ(csA, xa, ya); addQ(csB, xb, yb);
        }
    }

    // Prefetch registers for advancing the window to row rn:
    // add row rn+5, subtract row rn-6.
    float4 paxA, payA, paxB, payB, psxA, psyA, psxB, psyB;
    auto prefetch = [&](int rn) {
        if (rn >= r0 + STRIP) return;          // past last output row
        const int ra = rn + 5, rs = rn - 6;
        if (ra < IMG_H) {
            paxA = *(const float4*)(p1 + (size_t)ra * IMG_W + c4a);
            payA = *(const float4*)(p2 + (size_t)ra * IMG_W + c4a);
            paxB = *(const float4*)(p1 + (size_t)ra * IMG_W + c4b);
            payB = *(const float4*)(p2 + (size_t)ra * IMG_W + c4b);
        }
        if (rs >= 0) {
            psxA = *(const float4*)(p1 + (size_t)rs * IMG_W + c4a);
            psyA = *(const float4*)(p2 + (size_t)rs * IMG_W + c4a);
            psxB = *(const float4*)(p1 + (size_t)rs * IMG_W + c4b);
            psyB = *(const float4*)(p2 + (size_t)rs * IMG_W + c4b);
        }
    };
    auto consume = [&](int rn) {
        const int ra = rn + 5, rs = rn - 6;
        if (ra < IMG_H) { addQ(csA, paxA, payA); addQ(csB, paxB, payB); }
        if (rs >= 0)    { subQ(csA, psxA, psyA); subQ(csB, psxB, psyB); }
    };

    auto writeSQ = [&]() {
#pragma unroll
        for (int ch = 0; ch < 4; ++ch) {
            *(float4*)&V[ch][8 + c4a] =
                make_float4(csA[ch][0], csA[ch][1], csA[ch][2], csA[ch][3]);
            *(float4*)&V[ch][8 + c4b] =
                make_float4(csB[ch][0], csB[ch][1], csB[ch][2], csB[ch][3]);
            V[ch][SSZ + 2 + t]      = (csA[ch][0] + csA[ch][1]) + (csA[ch][2] + csA[ch][3]);
            V[ch][SSZ + 2 + 64 + t] = (csB[ch][0] + csB[ch][1]) + (csB[ch][2] + csB[ch][3]);
        }
    };

    // H-phase offsets: lane handles px cols c = t + 64k, k=0..7; all share
    // residue rho = t&3, so one offset set + compile-time +64k/+16k folds
    // into ds_read immediates.
    int sOff[3], qOff[2];
    {
        const int rho = t & 3;
        int e0, e1, e2;
        if (rho == 0)      { e0 = -5; e1 =  4; e2 =  5; }
        else if (rho == 1) { e0 =  3; e1 =  4; e2 =  5; }
        else if (rho == 2) { e0 = -5; e1 = -4; e2 = -3; }
        else               { e0 = -5; e1 = -4; e2 =  5; }
        sOff[0] = t + 8 + e0; sOff[1] = t + 8 + e1; sOff[2] = t + 8 + e2;
        const int mlo = (t >> 2) + ((rho < 2) ? -1 : 0);
        qOff[0] = SSZ + 2 + mlo; qOff[1] = SSZ + 3 + mlo;
    }

    constexpr float inv  = 1.0f / 121.0f;
    constexpr float inv2 = 0.5f / 121.0f;
    constexpr float C1c = 0.01f * 0.01f;
    constexpr float C2c = 0.03f * 0.03f;
    float acc = 0.0f;
    const float* __restrict__ Vf = &V[0][0];

    auto hphase = [&]() {
#pragma unroll
        for (int k = 0; k < 8; ++k) {
            float W[4];
#pragma unroll
            for (int ch = 0; ch < 4; ++ch) {
                const int base = ch * ROWSZ;
                W[ch] = ((Vf[base + sOff[0] + 64 * k] + Vf[base + sOff[1] + 64 * k]) +
                         (Vf[base + sOff[2] + 64 * k] + Vf[base + qOff[0] + 16 * k])) +
                        Vf[base + qOff[1] + 16 * k];
            }
            float mu_u = W[0] * inv, mu_v = W[1] * inv;
            float uu = mu_u * mu_u, vv = mu_v * mu_v;
            float P = 0.5f * (uu + vv);             // mu1^2 + mu2^2
            float M = 0.5f * (uu - vv);             // 2*mu1*mu2
            float A = fmaf(W[2] + W[3], inv2, -P);  // sig1^2 + sig2^2
            float B = fmaf(W[2] - W[3], inv2, -M);  // 2*sig12
            float num = (M + C1c) * (B + C2c);
            float den = (P + C1c) * (A + C2c);
            acc += __fdividef(num, den);
        }
    };

    // Main pipeline, barrier-free: same-wave LDS pipe is in-order, so the
    // writeSQ for row r+1 cannot pass hphase's reads of row r; prefetched
    // global loads stay in flight across the whole row (consumed next iter).
    writeSQ();                 // S/Q for row r0
    prefetch(r0 + 1);
    for (int i = 0; i < STRIP - 1; ++i) {
        hphase();              // SSIM for row r0+i
        consume(r0 + i + 1);   // implicit vmcnt wait: loads issued 1 row ago
        prefetch(r0 + i + 2);  // issue next loads; no barrier will drain them
        writeSQ();             // S/Q for row r0+i+1 (overwrites, same wave)
    }
    hphase();                  // last row

    // Reduce: intra-wave shuffle tree -> one atomic per wave.
#pragma unroll
    for (int off = 32; off > 0; off >>= 1) acc += __shfl_down(acc, off);
    if (t == 0) atomicAdd(ws, acc);
}

__global__ void ssim_finalize(const float* __restrict__ ws, float* __restrict__ out) {
    constexpr float inv_n = 1.0f / (float)((size_t)N_IMG * IMG_H * IMG_W);
    out[0] = 1.0f - ws[0] * inv_n;
}

extern "C" void kernel_launch(void* const* d_in, const int* in_sizes, int n_in,
                              void* d_out, int out_size, void* d_ws, size_t ws_size,
                              hipStream_t stream) {
    const float* img1 = (const float*)d_in[0];
    const float* img2 = (const float*)d_in[1];
    float* out = (float*)d_out;
    float* ws = (float*)d_ws;

    hipMemsetAsync(ws, 0, sizeof(float), stream);

    dim3 grid(IMG_H / STRIP, N_IMG);   // (64, 64) = 4096 blocks, 1 wave each
    ssim_kernel<<<grid, NTHREADS, 0, stream>>>(img1, img2, ws);
    ssim_finalize<<<1, 1, 0, stream>>>(ws, out);
}

// Round 3
// 219.370 us; speedup vs baseline: 2.9285x; 2.9285x over previous
//
#include <hip/hip_runtime.h>

// SSIM loss, fused. R8: R7's wave-autonomous barrier-free structure with the
// register budget FIXED.
// R7 post-mortem: __launch_bounds__(64,4) drove the allocator to a 64-VGPR
// bin (8 waves/EU target); the ~110-reg working set (cs arrays + prefetch
// float4s) spilled to scratch -> WRITE_SIZE 64KB->1.16GB, FETCH +485MB,
// 580us/dispatch. Structure was right, budget was wrong.
// R8: __launch_bounds__(64,2) (256-VGPR cap). Everything else identical:
//  - one wave owns an 8-row x 512-col strip (8 cols/lane), wave-private LDS
//    S/Q buffers, ZERO barriers in the main loop (same-wave DS is in-order);
//  - u=x+y, v=x-y -> Su,Sv,Suu,Svv; 11-tap window = 3 S + 2 Q reads,
//    lane-stride-1 / broadcast (proven 0 LDS bank conflicts);
//  - register prefetch of next row's float4s, consumed one row later, never
//    drained by any barrier.
// Per-pixel arithmetic order identical to R5-R7 (absmax 0.0 expected).

#define IMG_H 512
#define IMG_W 512
#define N_IMG 64
#define STRIP 8            // output rows per wave -> grid (64,64)=4096 blocks
#define NTHREADS 64        // one wave per block
#define SSZ 528            // S: idx = col + 8, cols -8..519 (pads zero)
#define QSZ 132            // Q: idx = m + 2,  m = -2..129  (pads zero)
#define ROWSZ (SSZ + QSZ)  // 660 floats per ch (mult of 4 -> 16B align)

__global__ __launch_bounds__(NTHREADS, 2) void ssim_kernel(const float* __restrict__ img1,
                                                           const float* __restrict__ img2,
                                                           float* __restrict__ ws) {
    __shared__ __align__(16) float V[4][ROWSZ];  // wave-private; ch: u,v,uu,vv
    const int t = threadIdx.x;                   // lane 0..63
    const int b = blockIdx.y;
    const int r0 = blockIdx.x * STRIP;
    const float* __restrict__ p1 = img1 + (size_t)b * (IMG_H * IMG_W);
    const float* __restrict__ p2 = img2 + (size_t)b * (IMG_H * IMG_W);

    // Zero all of V once (pads never written again). Same wave -> in-order
    // LDS pipe, no barrier needed.
    for (int i = t; i < 4 * ROWSZ; i += NTHREADS) (&V[0][0])[i] = 0.0f;

    // Lane owns cols c4a..c4a+3 and c4b..c4b+3 (two float4 quads).
    const int c4a = 4 * t;
    const int c4b = 4 * t + 256;
    float csA[4][4], csB[4][4];
#pragma unroll
    for (int ch = 0; ch < 4; ++ch)
#pragma unroll
        for (int j = 0; j < 4; ++j) { csA[ch][j] = 0.0f; csB[ch][j] = 0.0f; }

    auto addQ = [&](float (&cs)[4][4], float4 x, float4 y) {
        float xs[4] = {x.x, x.y, x.z, x.w}, ys[4] = {y.x, y.y, y.z, y.w};
#pragma unroll
        for (int j = 0; j < 4; ++j) {
            float u = xs[j] + ys[j], v = xs[j] - ys[j];
            cs[0][j] += u;                  cs[1][j] += v;
            cs[2][j] = fmaf(u, u, cs[2][j]); cs[3][j] = fmaf(v, v, cs[3][j]);
        }
    };
    auto subQ = [&](float (&cs)[4][4], float4 x, float4 y) {
        float xs[4] = {x.x, x.y, x.z, x.w}, ys[4] = {y.x, y.y, y.z, y.w};
#pragma unroll
        for (int j = 0; j < 4; ++j) {
            float u = xs[j] + ys[j], v = xs[j] - ys[j];
            cs[0][j] -= u;                  cs[1][j] -= v;
            cs[2][j] = fmaf(-u, u, cs[2][j]); cs[3][j] = fmaf(-v, v, cs[3][j]);
        }
    };

    // Warm vertical window for output row r0. Static 11-iter unrolled loop
    // (predicated top edge) so the compiler can issue loads ahead.
#pragma unroll
    for (int dr = -5; dr <= 5; ++dr) {
        const int r = r0 + dr;                 // r0+5 <= 509 < IMG_H always
        if (r >= 0) {
            float4 xa = *(const float4*)(p1 + (size_t)r * IMG_W + c4a);
            float4 ya = *(const float4*)(p2 + (size_t)r * IMG_W + c4a);
            float4 xb = *(const float4*)(p1 + (size_t)r * IMG_W + c4b);
            float4 yb = *(const float4*)(p2 + (size_t)r * IMG_W + c4b);
            addQ(csA, xa, ya); addQ(csB, xb, yb);
        }
    }

    // Prefetch registers for advancing the window to row rn:
    // add row rn+5, subtract row rn-6.
    float4 paxA, payA, paxB, payB, psxA, psyA, psxB, psyB;
    auto prefetch = [&](int rn) {
        if (rn >= r0 + STRIP) return;          // past last output row
        const int ra = rn + 5, rs = rn - 6;
        if (ra < IMG_H) {
            paxA = *(const float4*)(p1 + (size_t)ra * IMG_W + c4a);
            payA = *(const float4*)(p2 + (size_t)ra * IMG_W + c4a);
            paxB = *(const float4*)(p1 + (size_t)ra * IMG_W + c4b);
            payB = *(const float4*)(p2 + (size_t)ra * IMG_W + c4b);
        }
        if (rs >= 0) {
            psxA = *(const float4*)(p1 + (size_t)rs * IMG_W + c4a);
            psyA = *(const float4*)(p2 + (size_t)rs * IMG_W + c4a);
            psxB = *(const float4*)(p1 + (size_t)rs * IMG_W + c4b);
            psyB = *(const float4*)(p2 + (size_t)rs * IMG_W + c4b);
        }
    };
    auto consume = [&](int rn) {
        const int ra = rn + 5, rs = rn - 6;
        if (ra < IMG_H) { addQ(csA, paxA, payA); addQ(csB, paxB, payB); }
        if (rs >= 0)    { subQ(csA, psxA, psyA); subQ(csB, psxB, psyB); }
    };

    auto writeSQ = [&]() {
#pragma unroll
        for (int ch = 0; ch < 4; ++ch) {
            *(float4*)&V[ch][8 + c4a] =
                make_float4(csA[ch][0], csA[ch][1], csA[ch][2], csA[ch][3]);
            *(float4*)&V[ch][8 + c4b] =
                make_float4(csB[ch][0], csB[ch][1], csB[ch][2], csB[ch][3]);
            V[ch][SSZ + 2 + t]      = (csA[ch][0] + csA[ch][1]) + (csA[ch][2] + csA[ch][3]);
            V[ch][SSZ + 2 + 64 + t] = (csB[ch][0] + csB[ch][1]) + (csB[ch][2] + csB[ch][3]);
        }
    };

    // H-phase offsets: lane handles px cols c = t + 64k, k=0..7; all share
    // residue rho = t&3, so one offset set + compile-time +64k/+16k folds
    // into ds_read immediates.
    int sOff[3], qOff[2];
    {
        const int rho = t & 3;
        int e0, e1, e2;
        if (rho == 0)      { e0 = -5; e1 =  4; e2 =  5; }
        else if (rho == 1) { e0 =  3; e1 =  4; e2 =  5; }
        else if (rho == 2) { e0 = -5; e1 = -4; e2 = -3; }
        else               { e0 = -5; e1 = -4; e2 =  5; }
        sOff[0] = t + 8 + e0; sOff[1] = t + 8 + e1; sOff[2] = t + 8 + e2;
        const int mlo = (t >> 2) + ((rho < 2) ? -1 : 0);
        qOff[0] = SSZ + 2 + mlo; qOff[1] = SSZ + 3 + mlo;
    }

    constexpr float inv  = 1.0f / 121.0f;
    constexpr float inv2 = 0.5f / 121.0f;
    constexpr float C1c = 0.01f * 0.01f;
    constexpr float C2c = 0.03f * 0.03f;
    float acc = 0.0f;
    const float* __restrict__ Vf = &V[0][0];

    auto hphase = [&]() {
#pragma unroll
        for (int k = 0; k < 8; ++k) {
            float W[4];
#pragma unroll
            for (int ch = 0; ch < 4; ++ch) {
                const int base = ch * ROWSZ;
                W[ch] = ((Vf[base + sOff[0] + 64 * k] + Vf[base + sOff[1] + 64 * k]) +
                         (Vf[base + sOff[2] + 64 * k] + Vf[base + qOff[0] + 16 * k])) +
                        Vf[base + qOff[1] + 16 * k];
            }
            float mu_u = W[0] * inv, mu_v = W[1] * inv;
            float uu = mu_u * mu_u, vv = mu_v * mu_v;
            float P = 0.5f * (uu + vv);             // mu1^2 + mu2^2
            float M = 0.5f * (uu - vv);             // 2*mu1*mu2
            float A = fmaf(W[2] + W[3], inv2, -P);  // sig1^2 + sig2^2
            float B = fmaf(W[2] - W[3], inv2, -M);  // 2*sig12
            float num = (M + C1c) * (B + C2c);
            float den = (P + C1c) * (A + C2c);
            acc += __fdividef(num, den);
        }
    };

    // Main pipeline, barrier-free: same-wave LDS pipe is in-order, so the
    // writeSQ for row r+1 cannot pass hphase's reads of row r; prefetched
    // global loads stay in flight across the whole row (consumed next iter).
    writeSQ();                 // S/Q for row r0
    prefetch(r0 + 1);
    for (int i = 0; i < STRIP - 1; ++i) {
        hphase();              // SSIM for row r0+i
        consume(r0 + i + 1);   // implicit vmcnt wait: loads issued 1 row ago
        prefetch(r0 + i + 2);  // issue next loads; no barrier will drain them
        writeSQ();             // S/Q for row r0+i+1 (overwrites, same wave)
    }
    hphase();                  // last row

    // Reduce: intra-wave shuffle tree -> one atomic per wave.
#pragma unroll
    for (int off = 32; off > 0; off >>= 1) acc += __shfl_down(acc, off);
    if (t == 0) atomicAdd(ws, acc);
}

__global__ void ssim_finalize(const float* __restrict__ ws, float* __restrict__ out) {
    constexpr float inv_n = 1.0f / (float)((size_t)N_IMG * IMG_H * IMG_W);
    out[0] = 1.0f - ws[0] * inv_n;
}

extern "C" void kernel_launch(void* const* d_in, const int* in_sizes, int n_in,
                              void* d_out, int out_size, void* d_ws, size_t ws_size,
                              hipStream_t stream) {
    const float* img1 = (const float*)d_in[0];
    const float* img2 = (const float*)d_in[1];
    float* out = (float*)d_out;
    float* ws = (float*)d_ws;

    hipMemsetAsync(ws, 0, sizeof(float), stream);

    dim3 grid(IMG_H / STRIP, N_IMG);   // (64, 64) = 4096 blocks, 1 wave each
    ssim_kernel<<<grid, NTHREADS, 0, stream>>>(img1, img2, ws);
    ssim_finalize<<<1, 1, 0, stream>>>(ws, out);
}

// Round 4
// 192.804 us; speedup vs baseline: 3.3320x; 1.1378x over previous
//
#include <hip/hip_runtime.h>

// SSIM loss, fused. R9: R6's structure with the pipeline ORDER fixed.
// R6 post-mortem: prefetch was issued immediately before __syncthreads();
// since the barrier compiles to s_waitcnt vmcnt(0) lgkmcnt(0) + s_barrier,
// the full ~700cy load latency was exposed at every barrier (104us/disp).
// R8 post-mortem: wave-autonomous STRIP=8 removed barriers but doubled the
// vertical halo (FETCH 161->204MB) and halved latency-hiding -> 137us.
// R9 = R5/R6 base (128 thr, STRIP=16, minimal halo, proven conflict-free
// S/Q layout) with loop body reordered:
//     consume(i+1) -> prefetch(i+2) -> writeSQ(i+1) -> hphase(i) -> barrier
// The prefetched loads now have writeSQ + ALL of hphase (~800+ cy of LDS/
// VALU work) before the barrier drain -> drain is free. Single prefetch
// register set (consume frees regs right before prefetch reuses them).
// Prefetch loads are unconditional (row-clamped) to keep one branchless
// VMEM block; add/sub guards in consume stay block-uniform scalar branches.
// Per-pixel arithmetic order identical to R5-R8 (absmax 0.0 expected).

#define IMG_H 512
#define IMG_W 512
#define N_IMG 64
#define STRIP 16           // output rows per block -> grid (32,64)=2048 blocks
#define NTHREADS 128
#define SSZ 528            // S: idx = col + 8, cols -8..519 (pads zero)
#define QSZ 132            // Q: idx = m + 2,  m = -2..129  (pads zero)
#define ROWSZ (SSZ + QSZ)  // 660 floats per [buf][ch] (mult of 4 -> 16B align)

__global__ __launch_bounds__(NTHREADS) void ssim_kernel(const float* __restrict__ img1,
                                                        const float* __restrict__ img2,
                                                        float* __restrict__ ws) {
    __shared__ __align__(16) float V[2][4][ROWSZ];  // double buffer; ch: u,v,uu,vv
    __shared__ float wsum[2];
    const int t = threadIdx.x;
    const int b = blockIdx.y;
    const int r0 = blockIdx.x * STRIP;
    const float* __restrict__ p1 = img1 + (size_t)b * (IMG_H * IMG_W);
    const float* __restrict__ p2 = img2 + (size_t)b * (IMG_H * IMG_W);

    // Zero all of V once; pad regions are never written after this.
    for (int i = t; i < 2 * 4 * ROWSZ; i += NTHREADS) (&V[0][0][0])[i] = 0.0f;

    // --- V phase: thread owns 4 adjacent cols c4..c4+3 (float4 loads) ---
    const int c4 = 4 * t;
    float cs[4][4];
#pragma unroll
    for (int ch = 0; ch < 4; ++ch)
#pragma unroll
        for (int j = 0; j < 4; ++j) cs[ch][j] = 0.0f;

    auto addrow = [&](int r) {
        float4 x = *(const float4*)(p1 + (size_t)r * IMG_W + c4);
        float4 y = *(const float4*)(p2 + (size_t)r * IMG_W + c4);
        float xs[4] = {x.x, x.y, x.z, x.w}, ys[4] = {y.x, y.y, y.z, y.w};
#pragma unroll
        for (int j = 0; j < 4; ++j) {
            float u = xs[j] + ys[j], v = xs[j] - ys[j];
            cs[0][j] += u;                  cs[1][j] += v;
            cs[2][j] = fmaf(u, u, cs[2][j]); cs[3][j] = fmaf(v, v, cs[3][j]);
        }
    };

    // Prefetch registers: rows to advance the window to row rn
    // (add rn+5, subtract rn-6). Loads are row-CLAMPED and unconditional;
    // consume() applies the real boundary conditions.
    float4 pax, pay, psx, psy;
    auto prefetch = [&](int rn) {
        int ra = rn + 5; if (ra > IMG_H - 1) ra = IMG_H - 1;
        int rs = rn - 6; if (rs < 0) rs = 0;
        pax = *(const float4*)(p1 + (size_t)ra * IMG_W + c4);
        pay = *(const float4*)(p2 + (size_t)ra * IMG_W + c4);
        psx = *(const float4*)(p1 + (size_t)rs * IMG_W + c4);
        psy = *(const float4*)(p2 + (size_t)rs * IMG_W + c4);
    };
    auto consume = [&](int rn) {
        if (rn + 5 < IMG_H) {   // block-uniform
            float xs[4] = {pax.x, pax.y, pax.z, pax.w};
            float ys[4] = {pay.x, pay.y, pay.z, pay.w};
#pragma unroll
            for (int j = 0; j < 4; ++j) {
                float u = xs[j] + ys[j], v = xs[j] - ys[j];
                cs[0][j] += u;                  cs[1][j] += v;
                cs[2][j] = fmaf(u, u, cs[2][j]); cs[3][j] = fmaf(v, v, cs[3][j]);
            }
        }
        if (rn - 6 >= 0) {      // block-uniform
            float xs[4] = {psx.x, psx.y, psx.z, psx.w};
            float ys[4] = {psy.x, psy.y, psy.z, psy.w};
#pragma unroll
            for (int j = 0; j < 4; ++j) {
                float u = xs[j] + ys[j], v = xs[j] - ys[j];
                cs[0][j] -= u;                  cs[1][j] -= v;
                cs[2][j] = fmaf(-u, u, cs[2][j]); cs[3][j] = fmaf(-v, v, cs[3][j]);
            }
        }
    };
    auto writeSQ = [&](int p) {
#pragma unroll
        for (int ch = 0; ch < 4; ++ch) {
            *(float4*)&V[p][ch][8 + c4] =
                make_float4(cs[ch][0], cs[ch][1], cs[ch][2], cs[ch][3]);
            V[p][ch][SSZ + 2 + t] = (cs[ch][0] + cs[ch][1]) + (cs[ch][2] + cs[ch][3]);
        }
    };

    // --- H phase offsets: px cols t+128k share residue rho = t&3 ---
    int offS[4][3], offQ[4][2];
#pragma unroll
    for (int k = 0; k < 4; ++k) {
        const int c = t + 128 * k;
        const int rho = c & 3;
        int e0, e1, e2;
        if (rho == 0)      { e0 = -5; e1 =  4; e2 =  5; }
        else if (rho == 1) { e0 =  3; e1 =  4; e2 =  5; }
        else if (rho == 2) { e0 = -5; e1 = -4; e2 = -3; }
        else               { e0 = -5; e1 = -4; e2 =  5; }
        offS[k][0] = c + 8 + e0; offS[k][1] = c + 8 + e1; offS[k][2] = c + 8 + e2;
        const int mlo = (c >> 2) + ((rho < 2) ? -1 : 0);
        offQ[k][0] = SSZ + 2 + mlo; offQ[k][1] = SSZ + 3 + mlo;
    }

    // Warm vertical window for output row r0 (zero pad outside image).
    {
        int rlo = r0 - 5; if (rlo < 0) rlo = 0;
        const int rhi = r0 + 5;              // r0 <= 496 -> rhi <= 501 < 512
        for (int r = rlo; r <= rhi; ++r) addrow(r);
    }
    __syncthreads();          // LDS zeroing complete
    writeSQ(0);               // S/Q for row r0 into buf 0
    prefetch(r0 + 1);         // loads for row r0+1 (drained once, prologue only)
    __syncthreads();          // buf 0 visible

    constexpr float inv  = 1.0f / 121.0f;
    constexpr float inv2 = 0.5f / 121.0f;
    constexpr float C1c = 0.01f * 0.01f;
    constexpr float C2c = 0.03f * 0.03f;
    float acc = 0.0f;

    auto hphase = [&](int p) {
        const float* __restrict__ Vf = &V[p][0][0];
#pragma unroll
        for (int k = 0; k < 4; ++k) {
            float W[4];
#pragma unroll
            for (int ch = 0; ch < 4; ++ch) {
                const int base = ch * ROWSZ;
                W[ch] = ((Vf[base + offS[k][0]] + Vf[base + offS[k][1]]) +
                         (Vf[base + offS[k][2]] + Vf[base + offQ[k][0]])) +
                        Vf[base + offQ[k][1]];
            }
            float mu_u = W[0] * inv, mu_v = W[1] * inv;
            float uu = mu_u * mu_u, vv = mu_v * mu_v;
            float P = 0.5f * (uu + vv);             // mu1^2 + mu2^2
            float M = 0.5f * (uu - vv);             // 2*mu1*mu2
            float A = fmaf(W[2] + W[3], inv2, -P);  // sig1^2 + sig2^2
            float B = fmaf(W[2] - W[3], inv2, -M);  // 2*sig12
            float num = (M + C1c) * (B + C2c);
            float den = (P + C1c) * (A + C2c);
            acc += __fdividef(num, den);
        }
    };

    // Main pipeline, one barrier per row, loads never exposed at the drain:
    //   consume(i+1): waits on loads issued one FULL iteration ago (done);
    //   prefetch(i+2): issues loads, then writeSQ+hphase (~800+cy) run
    //                  before the barrier's vmcnt(0) -> drain is free;
    //   writeSQ(i+1) -> buf !p; hphase(i) -> buf p (disjoint, no WAR).
    for (int i = 0; i < STRIP - 1; ++i) {
        consume(r0 + i + 1);
        int rn = r0 + i + 2;                       // clamped redundant load on
        if (rn > r0 + STRIP - 1) rn = r0 + STRIP - 1;  // the last iteration
        prefetch(rn);
        writeSQ((i + 1) & 1);
        hphase(i & 1);
        __syncthreads();
    }
    hphase((STRIP - 1) & 1);      // last row

    // Reduce: wave shuffle -> LDS -> one atomic per block.
#pragma unroll
    for (int off = 32; off > 0; off >>= 1) acc += __shfl_down(acc, off);
    if ((t & 63) == 0) wsum[t >> 6] = acc;
    __syncthreads();
    if (t == 0) atomicAdd(ws, wsum[0] + wsum[1]);
}

__global__ void ssim_finalize(const float* __restrict__ ws, float* __restrict__ out) {
    constexpr float inv_n = 1.0f / (float)((size_t)N_IMG * IMG_H * IMG_W);
    out[0] = 1.0f - ws[0] * inv_n;
}

extern "C" void kernel_launch(void* const* d_in, const int* in_sizes, int n_in,
                              void* d_out, int out_size, void* d_ws, size_t ws_size,
                              hipStream_t stream) {
    const float* img1 = (const float*)d_in[0];
    const float* img2 = (const float*)d_in[1];
    float* out = (float*)d_out;
    float* ws = (float*)d_ws;

    hipMemsetAsync(ws, 0, sizeof(float), stream);

    dim3 grid(IMG_H / STRIP, N_IMG);   // (32, 64) = 2048 blocks
    ssim_kernel<<<grid, NTHREADS, 0, stream>>>(img1, img2, ws);
    ssim_finalize<<<1, 1, 0, stream>>>(ws, out);
}

// Round 5
// 183.727 us; speedup vs baseline: 3.4966x; 1.0494x over previous
//
#include <hip/hip_runtime.h>

// SSIM loss, fused. R10: fix the GENERATION QUANTIZATION found in R9.
// R9 post-mortem: LDS 21.5KB -> only 7 blocks/CU resident, but grid puts
// 8/CU -> two generations (7 blocks, then 1 with the CU idle). Predicted
// avg occupancy (14+2)/2 = 8 waves = 25%; measured 27%. Wall = 2x block_dur.
// R10: width-split blocks: 128 threads cover 256 cols x STRIP=32 rows,
// lane owns 2 cols (float2 loads). LDS halves to ~11KB -> 14 blocks/CU
// possible, 8 assigned -> SINGLE generation, 16 waves/CU resident.
// STRIP=32 also cuts vertical halo 1.625x -> 1.31x. Column seam (5 cols)
// handled by threads 0..7 keeping one extra halo column-sum pair.
// Preserved from R5-R9 (proven): S/Q two-level horizontal sums (11-tap =
// 3 S + 2 Q reads, lane-stride-1 / broadcast, 0 bank conflicts); same
// summation order (Q = (s0+s1)+(s2+s3), here via one __shfl_down); R9's
// pipeline order consume -> prefetch -> writeSQ -> hphase -> barrier so
// the barrier's vmcnt(0) drain stays covered by ~800cy of LDS/VALU work.

#define IMG_H 512
#define IMG_W 512
#define N_IMG 64
#define STRIP 32           // rows per block
#define BCOLS 256          // output cols per block
#define NTHREADS 128
#define SSZ 272            // S: idx = cl + 8, cl in [-8, 263] (pads zero)
#define QSZ 68             // Q: idx = m + 2,  m in [-2, 65]  (pads zero)
#define ROWSZ (SSZ + QSZ)  // 340 floats per [buf][ch] (mult of 4 -> 16B align)

__global__ __launch_bounds__(NTHREADS) void ssim_kernel(const float* __restrict__ img1,
                                                        const float* __restrict__ img2,
                                                        float* __restrict__ ws) {
    __shared__ __align__(16) float V[2][4][ROWSZ];  // double buffer; ch: u,v,uu,vv
    __shared__ float wsum[2];
    const int t = threadIdx.x;
    const int b = blockIdx.y;
    const int sx = blockIdx.x >> 1;      // row-strip index
    const int half = blockIdx.x & 1;     // column half
    const int r0 = sx * STRIP;
    const int cbase = half * BCOLS;
    const float* __restrict__ p1 = img1 + (size_t)b * (IMG_H * IMG_W);
    const float* __restrict__ p2 = img2 + (size_t)b * (IMG_H * IMG_W);

    // Zero all of V once; pad regions are never written after this.
    for (int i = t; i < 2 * 4 * ROWSZ; i += NTHREADS) (&V[0][0][0])[i] = 0.0f;

    // Main cols: lane owns img cols cm, cm+1. Halo cols: threads 0..7 own
    // one extra pair just outside [cbase, cbase+255] (zero-pad if outside
    // the image; S/Q for invalid sides stay 0 from the init above).
    const int cm = cbase + 2 * t;
    const int hloc = (t < 4) ? (-8 + 2 * t) : (256 + 2 * (t - 4));  // local
    const int hcol = cbase + hloc;                                   // image
    const bool hval = (t < 8) && (hcol >= 0) && (hcol <= IMG_W - 2);

    float cs[4][2], csH[4][2];
#pragma unroll
    for (int ch = 0; ch < 4; ++ch)
#pragma unroll
        for (int j = 0; j < 2; ++j) { cs[ch][j] = 0.0f; csH[ch][j] = 0.0f; }

    auto addPair = [&](float (&a)[4][2], float2 x, float2 y) {
#pragma unroll
        for (int j = 0; j < 2; ++j) {
            float xv = j ? x.y : x.x, yv = j ? y.y : y.x;
            float u = xv + yv, v = xv - yv;
            a[0][j] += u;                   a[1][j] += v;
            a[2][j] = fmaf(u, u, a[2][j]);  a[3][j] = fmaf(v, v, a[3][j]);
        }
    };
    auto subPair = [&](float (&a)[4][2], float2 x, float2 y) {
#pragma unroll
        for (int j = 0; j < 2; ++j) {
            float xv = j ? x.y : x.x, yv = j ? y.y : y.x;
            float u = xv + yv, v = xv - yv;
            a[0][j] -= u;                   a[1][j] -= v;
            a[2][j] = fmaf(-u, u, a[2][j]); a[3][j] = fmaf(-v, v, a[3][j]);
        }
    };

    // Warm vertical window for output row r0 (zero pad above the image).
    {
        int rlo = r0 - 5; if (rlo < 0) rlo = 0;
        const int rhi = r0 + 5;          // r0 <= 480 -> rhi <= 485 < 512
        for (int r = rlo; r <= rhi; ++r) {
            float2 x = *(const float2*)(p1 + (size_t)r * IMG_W + cm);
            float2 y = *(const float2*)(p2 + (size_t)r * IMG_W + cm);
            addPair(cs, x, y);
            if (hval) {
                float2 hx = *(const float2*)(p1 + (size_t)r * IMG_W + hcol);
                float2 hy = *(const float2*)(p2 + (size_t)r * IMG_W + hcol);
                addPair(csH, hx, hy);
            }
        }
    }

    // Prefetch registers: rows to advance the window to row rn
    // (add rn+5, subtract rn-6). Row-clamped unconditional main loads;
    // consume() applies the real boundary conditions.
    float2 pax, pay, psx, psy, hax, hay, hsx, hsy;
    auto prefetch = [&](int rn) {
        int ra = rn + 5; if (ra > IMG_H - 1) ra = IMG_H - 1;
        int rs = rn - 6; if (rs < 0) rs = 0;
        pax = *(const float2*)(p1 + (size_t)ra * IMG_W + cm);
        pay = *(const float2*)(p2 + (size_t)ra * IMG_W + cm);
        psx = *(const float2*)(p1 + (size_t)rs * IMG_W + cm);
        psy = *(const float2*)(p2 + (size_t)rs * IMG_W + cm);
        if (hval) {
            hax = *(const float2*)(p1 + (size_t)ra * IMG_W + hcol);
            hay = *(const float2*)(p2 + (size_t)ra * IMG_W + hcol);
            hsx = *(const float2*)(p1 + (size_t)rs * IMG_W + hcol);
            hsy = *(const float2*)(p2 + (size_t)rs * IMG_W + hcol);
        }
    };
    auto consume = [&](int rn) {
        if (rn + 5 < IMG_H) {   // block-uniform
            addPair(cs, pax, pay);
            if (hval) addPair(csH, hax, hay);
        }
        if (rn - 6 >= 0) {      // block-uniform
            subPair(cs, psx, psy);
            if (hval) subPair(csH, hsx, hsy);
        }
    };

    auto writeSQ = [&](int p) {
#pragma unroll
        for (int ch = 0; ch < 4; ++ch) {
            *(float2*)&V[p][ch][8 + 2 * t] = make_float2(cs[ch][0], cs[ch][1]);
            float ps = cs[ch][0] + cs[ch][1];
            float nb = __shfl_down(ps, 1);
            if ((t & 1) == 0) V[p][ch][SSZ + 2 + (t >> 1)] = ps + nb;  // m = t/2
            // Halo S + halo quads m=-2,-1 (idx 0,1) and m=64,65 (idx 66,67).
            float psH = csH[ch][0] + csH[ch][1];
            float nbH = __shfl_down(psH, 1);
            if (t < 8) {
                *(float2*)&V[p][ch][8 + hloc] = make_float2(csH[ch][0], csH[ch][1]);
                if ((t & 1) == 0) {
                    const int qi = (t < 4) ? (t >> 1) : (64 + (t >> 1));
                    V[p][ch][SSZ + qi] = psH + nbH;
                }
            }
        }
    };

    // --- H phase offsets: px local cols t and t+128 share rho = t&3 ---
    int sOff[3], q0;
    {
        const int rho = t & 3;
        int e0, e1, e2;
        if (rho == 0)      { e0 = -5; e1 =  4; e2 =  5; }
        else if (rho == 1) { e0 =  3; e1 =  4; e2 =  5; }
        else if (rho == 2) { e0 = -5; e1 = -4; e2 = -3; }
        else               { e0 = -5; e1 = -4; e2 =  5; }
        sOff[0] = t + 8 + e0; sOff[1] = t + 8 + e1; sOff[2] = t + 8 + e2;
        const int mlo = (t >> 2) + ((rho < 2) ? -1 : 0);
        q0 = SSZ + 2 + mlo;
    }

    __syncthreads();          // LDS zeroing complete
    writeSQ(0);               // S/Q for row r0 into buf 0
    prefetch(r0 + 1);         // prologue-only exposed drain
    __syncthreads();          // buf 0 visible

    constexpr float inv  = 1.0f / 121.0f;
    constexpr float inv2 = 0.5f / 121.0f;
    constexpr float C1c = 0.01f * 0.01f;
    constexpr float C2c = 0.03f * 0.03f;
    float acc = 0.0f;

    auto hphase = [&](int p) {
#pragma unroll
        for (int k = 0; k < 2; ++k) {
            const int ds = 128 * k, dq = 32 * k;   // px local col t + 128k
            float W[4];
#pragma unroll
            for (int ch = 0; ch < 4; ++ch) {
                const float* __restrict__ Vf = &V[p][ch][0];
                W[ch] = ((Vf[sOff[0] + ds] + Vf[sOff[1] + ds]) +
                         (Vf[sOff[2] + ds] + Vf[q0 + dq])) +
                        Vf[q0 + 1 + dq];
            }
            float mu_u = W[0] * inv, mu_v = W[1] * inv;
            float uu = mu_u * mu_u, vv = mu_v * mu_v;
            float P = 0.5f * (uu + vv);             // mu1^2 + mu2^2
            float M = 0.5f * (uu - vv);             // 2*mu1*mu2
            float A = fmaf(W[2] + W[3], inv2, -P);  // sig1^2 + sig2^2
            float B = fmaf(W[2] - W[3], inv2, -M);  // 2*sig12
            float num = (M + C1c) * (B + C2c);
            float den = (P + C1c) * (A + C2c);
            acc += __fdividef(num, den);
        }
    };

    // Main pipeline (R9's proven order), one barrier per row:
    //   consume(i+1): loads issued one full iteration ago (done);
    //   prefetch(i+2): then writeSQ + hphase run before the barrier's
    //                  vmcnt(0) -> drain is free;
    //   writeSQ(i+1) -> buf !p; hphase(i) -> buf p (disjoint, no WAR).
    for (int i = 0; i < STRIP - 1; ++i) {
        consume(r0 + i + 1);
        int rn = r0 + i + 2;                           // clamped redundant
        if (rn > r0 + STRIP - 1) rn = r0 + STRIP - 1;  // load on last iter
        prefetch(rn);
        writeSQ((i + 1) & 1);
        hphase(i & 1);
        __syncthreads();
    }
    hphase((STRIP - 1) & 1);      // last row

    // Reduce: wave shuffle -> LDS -> one atomic per block.
#pragma unroll
    for (int off = 32; off > 0; off >>= 1) acc += __shfl_down(acc, off);
    if ((t & 63) == 0) wsum[t >> 6] = acc;
    __syncthreads();
    if (t == 0) atomicAdd(ws, wsum[0] + wsum[1]);
}

__global__ void ssim_finalize(const float* __restrict__ ws, float* __restrict__ out) {
    constexpr float inv_n = 1.0f / (float)((size_t)N_IMG * IMG_H * IMG_W);
    out[0] = 1.0f - ws[0] * inv_n;
}

extern "C" void kernel_launch(void* const* d_in, const int* in_sizes, int n_in,
                              void* d_out, int out_size, void* d_ws, size_t ws_size,
                              hipStream_t stream) {
    const float* img1 = (const float*)d_in[0];
    const float* img2 = (const float*)d_in[1];
    float* out = (float*)d_out;
    float* ws = (float*)d_ws;

    hipMemsetAsync(ws, 0, sizeof(float), stream);

    // (16 row-strips x 2 col-halves, 64 images) = 2048 blocks = 8/CU,
    // all resident in ONE generation (LDS 11.3KB -> 14/CU possible).
    dim3 grid((IMG_H / STRIP) * 2, N_IMG);
    ssim_kernel<<<grid, NTHREADS, 0, stream>>>(img1, img2, ws);
    ssim_finalize<<<1, 1, 0, stream>>>(ws, out);
}